// Round 8
// baseline (556.455 us; speedup 1.0000x reference)
//
#include <hip/hip_runtime.h>
#include <math.h>

#define VOCAB 32000
#define NB 16        // batch
#define NH 12        // heads
#define DEC_T 128
#define ALEN 512
#define DD 768
#define NT 256       // threads per block (lean blocks -> 8 blocks/CU)
#define NW 4         // waves per block
#define V4 8000      // VOCAB/4 float4 per row
#define HSZ 1024     // hash slots (pow2, >= 2*ALEN -> load factor <= 0.5)
#define HMASK (HSZ - 1)
#define BMW (VOCAB / 32)   // 1000 bitmap words
#define HEMPTY 0xFFFFFFFFu

__device__ inline float wave_sum(float v) {
#pragma unroll
  for (int o = 32; o > 0; o >>= 1) v += __shfl_down(v, o, 64);
  return v;
}
__device__ inline float wave_max(float v) {
#pragma unroll
  for (int o = 32; o > 0; o >>= 1) v = fmaxf(v, __shfl_down(v, o, 64));
  return v;
}

// Explicit 3-pass streaming structure (R7 counters showed the compiler was
// already rematerializing the "register cached" row from L2/L3 at VGPR=56).
// NT=256 + LDS 12.3KB + ~50 VGPR -> 8 blocks/CU = 32 waves/CU; the 2048-block
// grid is one fully-resident generation. Two-pass softmax: max pass has zero
// exp and no serial rescale chain; Z pass is 1 exp/elem. 2 barriers total.
__global__ __launch_bounds__(NT, 4) void pg_kernel(
    const float* __restrict__ dec, const float* __restrict__ fo,
    const float* __restrict__ attnw, const int* __restrict__ ids,
    const float* __restrict__ Wpg, const float* __restrict__ bpg,
    float* __restrict__ out) {
  __shared__ unsigned s_bm[BMW];     // presence bitmap, 4000 B
  __shared__ unsigned s_key[HSZ];    // hash keys, 4096 B
  __shared__ float    s_val[HSZ];    // hash values (raw ae sums), 4096 B
  __shared__ float    s_redA[NW];    // attn max partials
  __shared__ float    s_redB[NW];    // pgen dot partials
  __shared__ float    s_redC[NW];    // ae sum partials
  __shared__ float    s_redM[NW];    // row max partials
  __shared__ float    s_redZ[NW];    // row Z partials

  const int bt = blockIdx.x;          // b*DEC_T + t
  const int b = bt / DEC_T;
  const int t = bt - b * DEC_T;
  const int tid = threadIdx.x;
  const int lane = tid & 63;
  const int wid = tid >> 6;

  // ---------- phase 1 (barrier-free): small loads + row max ----------
  const float* ap = attnw + ((size_t)b * NH * DEC_T + t) * ALEN;
  float h0 = 0.f, h1 = 0.f;                 // positions tid, tid+NT (ALEN=2*NT)
#pragma unroll
  for (int h = 0; h < NH; ++h) {
    const float* aph = ap + (size_t)h * DEC_T * ALEN;
    h0 += aph[tid];
    h1 += aph[tid + NT];
  }
  const float* dp = dec + (size_t)bt * DD;  // DD = 3*NT
  float pp = dp[tid] * Wpg[tid] + dp[NT + tid] * Wpg[NT + tid] +
             dp[2 * NT + tid] * Wpg[2 * NT + tid];
  const unsigned id0 = (unsigned)ids[b * ALEN + tid];
  const unsigned id1 = (unsigned)ids[b * ALEN + NT + tid];

  // zero scatter structures (overlaps load latency)
  for (int i = tid; i < BMW; i += NT) s_bm[i] = 0u;
  for (int i = tid; i < HSZ; i += NT) { s_key[i] = HEMPTY; s_val[i] = 0.f; }

  // row max: pure fmax stream, no exp, no serial rescale
  const float4* row4 = (const float4*)(fo + (size_t)bt * VOCAB);
  float m = -INFINITY;
  for (int i = tid; i < V4; i += NT) {
    const float4 x = row4[i];
    m = fmaxf(m, fmaxf(fmaxf(x.x, x.y), fmaxf(x.z, x.w)));
  }
  m = wave_max(m);
  if (lane == 0) s_redM[wid] = m;

  const float amean0 = h0 * (1.f / NH);
  const float amean1 = h1 * (1.f / NH);
  float am = wave_max(fmaxf(amean0, amean1));
  if (lane == 0) s_redA[wid] = am;
  pp = wave_sum(pp);
  if (lane == 0) s_redB[wid] = pp;
  __syncthreads();                                     // B1

  // ---------- phase 2: folds; Z pass; ae + scatter ----------
  float fm = -INFINITY, amax = -INFINITY, pdot = 0.f;
#pragma unroll
  for (int i = 0; i < NW; ++i) {
    fm = fmaxf(fm, s_redM[i]);
    amax = fmaxf(amax, s_redA[i]);
    pdot += s_redB[i];
  }
  const float pgen = 1.f / (1.f + __expf(-(pdot + bpg[0])));

  // Z pass: re-stream the row (L2/L3-hot), 1 exp per element
  float zs = 0.f;
  for (int i = tid; i < V4; i += NT) {
    const float4 x = row4[i];
    zs += __expf(x.x - fm) + __expf(x.y - fm) +
          __expf(x.z - fm) + __expf(x.w - fm);
  }
  zs = wave_sum(zs);
  if (lane == 0) s_redZ[wid] = zs;

  // attn ae + scatter RAW ae (ainv applied at read); dups merged by atomicAdd
  const float ae0 = __expf(amean0 - amax);
  const float ae1 = __expf(amean1 - amax);
  float as = wave_sum(ae0 + ae1);
  if (lane == 0) s_redC[wid] = as;

  atomicOr(&s_bm[id0 >> 5], 1u << (id0 & 31));
  {
    unsigned h = (id0 * 2654435761u) >> 22;    // top 10 bits of Knuth hash
    for (;;) {
      unsigned old = atomicCAS(&s_key[h], HEMPTY, id0);
      if (old == HEMPTY || old == id0) { atomicAdd(&s_val[h], ae0); break; }
      h = (h + 1) & HMASK;                     // <=512 entries in 1024 slots
    }
  }
  atomicOr(&s_bm[id1 >> 5], 1u << (id1 & 31));
  {
    unsigned h = (id1 * 2654435761u) >> 22;
    for (;;) {
      unsigned old = atomicCAS(&s_key[h], HEMPTY, id1);
      if (old == HEMPTY || old == id1) { atomicAdd(&s_val[h], ae1); break; }
      h = (h + 1) & HMASK;
    }
  }
  __syncthreads();                                     // B2 (publishes scatter)

  // ---------- phase 3: fold Z/asum; output ----------
  float Z = 0.f, asum = 0.f;
#pragma unroll
  for (int i = 0; i < NW; ++i) {
    Z += s_redZ[i];
    asum += s_redC[i];
  }
  const float ainv = (1.f - pgen) / asum;
  const float invZ = 1.f / Z;
  const float C = __logf(pgen) - fm - __logf(Z);

  auto hget = [&](unsigned id) -> float {
    unsigned h = (id * 2654435761u) >> 22;
    while (s_key[h] != id) h = (h + 1) & HMASK;  // bitmap bit set => present
    return s_val[h];
  };

  // output: re-stream the row; scatter==0 fast path (~98.4%) is x + C
  float4* out4 = (float4*)(out + (size_t)bt * VOCAB);
  for (int i = tid; i < V4; i += NT) {
    const float4 x = row4[i];
    const unsigned nib = (s_bm[i >> 3] >> ((i & 7) * 4)) & 0xFu;
    float4 o;
    if (nib == 0u) {
      o.x = x.x + C; o.y = x.y + C; o.z = x.z + C; o.w = x.w + C;
    } else {
      const unsigned v = (unsigned)i * 4u;
      o.x = (nib & 1u) ? __logf(pgen * __expf(x.x - fm) * invZ + hget(v + 0u) * ainv) : (x.x + C);
      o.y = (nib & 2u) ? __logf(pgen * __expf(x.y - fm) * invZ + hget(v + 1u) * ainv) : (x.y + C);
      o.z = (nib & 4u) ? __logf(pgen * __expf(x.z - fm) * invZ + hget(v + 2u) * ainv) : (x.z + C);
      o.w = (nib & 8u) ? __logf(pgen * __expf(x.w - fm) * invZ + hget(v + 3u) * ainv) : (x.w + C);
    }
    out4[i] = o;
  }
}

extern "C" void kernel_launch(void* const* d_in, const int* in_sizes, int n_in,
                              void* d_out, int out_size, void* d_ws, size_t ws_size,
                              hipStream_t stream) {
  (void)in_sizes; (void)n_in; (void)out_size; (void)d_ws; (void)ws_size;
  const float* dec   = (const float*)d_in[0];   // (16,128,768)
  const float* fo    = (const float*)d_in[1];   // (16,128,32000)
  const float* attnw = (const float*)d_in[2];   // (16,12,128,512)
  const int*   ids   = (const int*)  d_in[3];   // (16,512)
  const float* Wpg   = (const float*)d_in[4];   // (768,1)
  const float* bpg   = (const float*)d_in[5];   // (1,)
  float* out = (float*)d_out;                   // (16,128,32000)

  pg_kernel<<<NB * DEC_T, NT, 0, stream>>>(dec, fo, attnw, ids, Wpg, bpg, out);
}